// Round 6
// baseline (217.204 us; speedup 1.0000x reference)
//
#include <hip/hip_runtime.h>
#include <hip/hip_fp16.h>

#define N_NODES 100000
#define N_EDGES 1600000
#define IN_DIM 128
#define OUT_DIM 64

#define PROJ_BLKS 1563  // ceil(N_NODES/64): 64 rows per block (4 waves x 16)

// Buckets of 128 nodes: bucket = dst >> 7.
#define NB2 782     // ceil(N_NODES/128)
#define MAXB2 2560  // Binom(1.6M,128/1e5): mean 2048, sigma 45; +11 sigma

// Deterministic run-slot binning: block qb owns slots [b*RUNTOT + qb*RUNCAP).
// No global atomics, no cursor memset, no cross-block ordering.
#define BIN_NBLK 100
#define BIN_CHUNK 16000  // BIN_NBLK * BIN_CHUNK == N_EDGES
#define RUNCAP 64        // Poisson(20.5) tail at 64: ~5e-14 per cell
#define RUNTOT (BIN_NBLK * RUNCAP)  // 6400 slots per bucket

#define PB_GRID (PROJ_BLKS + BIN_NBLK)  // bin blocks FIRST (co-resident)

#define SG_THREADS 512  // 8 waves; ~33KB LDS -> 4 blocks/CU

typedef short short8 __attribute__((ext_vector_type(8)));
typedef float f32x4 __attribute__((ext_vector_type(4)));

__device__ __forceinline__ short bf16_trunc(float x) {
  return (short)(__float_as_uint(x) >> 16);
}
__device__ __forceinline__ float bf16_tof(short s) {
  return __uint_as_float(((unsigned)(unsigned short)s) << 16);
}
__device__ __forceinline__ float edge_ex(float p) {
  float t2 = __expf(2.f * p);
  float th = 1.f - 2.f * __builtin_amdgcn_rcpf(t2 + 1.f);
  return __expf(th);
}

// ---- Fused: bin-scatter (blocks < BIN_NBLK, dispatched first) + MFMA proj --
__global__ __launch_bounds__(256) void fused_pb_kernel(
    const float* __restrict__ h_init, const float* __restrict__ W1,
    const float* __restrict__ a, const int* __restrict__ src,
    const int* __restrict__ dst, float* __restrict__ h,
    __half* __restrict__ h16, float* __restrict__ ha,
    unsigned int* __restrict__ pairs, unsigned char* __restrict__ cnt8) {
  __shared__ __align__(16) char smem[16 * 64 * 8 * 2 * sizeof(short)];  // 32KB

  if (blockIdx.x < BIN_NBLK) {
    // ---- bin branch: 1 LDS atomic + 1 bounded global write per edge ----
    int* cur = (int*)smem;  // NB2 ints
    int qb = blockIdx.x;
    for (int i = threadIdx.x; i < NB2; i += 256) cur[i] = 0;
    __syncthreads();
    int beg = qb * BIN_CHUNK;
    for (int e0 = threadIdx.x * 4; e0 < BIN_CHUNK; e0 += 256 * 4) {
      int4 s4 = *(const int4*)&src[beg + e0];
      int4 d4 = *(const int4*)&dst[beg + e0];
      int ss[4] = {s4.x, s4.y, s4.z, s4.w};
      int dd[4] = {d4.x, d4.y, d4.z, d4.w};
#pragma unroll
      for (int k = 0; k < 4; k++) {
        int b = dd[k] >> 7;
        int idx = atomicAdd(&cur[b], 1);
        if (idx < RUNCAP)
          pairs[(size_t)b * RUNTOT + qb * RUNCAP + idx] =
              ((unsigned)ss[k] << 7) | (unsigned)(dd[k] & 127);
      }
    }
    __syncthreads();
    for (int i = threadIdx.x; i < NB2; i += 256)
      cnt8[qb * NB2 + i] = (unsigned char)min(cur[i], RUNCAP);
    return;
  }

  // ---------------- projection branch (verified body) ----------------
  int pb = blockIdx.x - BIN_NBLK;
  short* whi = (short*)smem;  // 16*64*8 shorts
  short* wlo = whi + 16 * 64 * 8;

  // stage W as bf16 hi/lo B-fragments (frag f=kc*4+ot, B[k][n]=W1[ot*16+n][k])
  for (int idx = threadIdx.x; idx < 16 * 64; idx += 256) {
    int f = idx >> 6;
    int l = idx & 63;
    int kc = f >> 2, ot = f & 3;
    const float* wsrc =
        W1 + (ot * 16 + (l & 15)) * IN_DIM + kc * 32 + (l >> 4) * 8;
    short hi[8], lo[8];
#pragma unroll
    for (int j = 0; j < 8; j++) {
      float x = wsrc[j];
      short hv = bf16_trunc(x);
      hi[j] = hv;
      lo[j] = bf16_trunc(x - bf16_tof(hv));
    }
    *(short8*)&whi[idx * 8] = *(const short8*)hi;
    *(short8*)&wlo[idx * 8] = *(const short8*)lo;
  }

  int row0 = pb * 64;
  int w = threadIdx.x >> 6;
  int l = threadIdx.x & 63;
  int m = l & 15;
  int q = l >> 4;

  int arow = row0 + w * 16 + m;
  if (arow >= N_NODES) arow = N_NODES - 1;
  const float* xsrc = h_init + (size_t)arow * IN_DIM + q * 8;

  short8 ahi[4], alo[4];
#pragma unroll
  for (int kc = 0; kc < 4; kc++) {
    float xv[8];
    *(float4*)&xv[0] = *(const float4*)(xsrc + kc * 32);
    *(float4*)&xv[4] = *(const float4*)(xsrc + kc * 32 + 4);
    short hi[8], lo[8];
#pragma unroll
    for (int j = 0; j < 8; j++) {
      short hv = bf16_trunc(xv[j]);
      hi[j] = hv;
      lo[j] = bf16_trunc(xv[j] - bf16_tof(hv));
    }
    ahi[kc] = *(const short8*)hi;
    alo[kc] = *(const short8*)lo;
  }
  __syncthreads();

  f32x4 acc[4] = {{0.f, 0.f, 0.f, 0.f},
                  {0.f, 0.f, 0.f, 0.f},
                  {0.f, 0.f, 0.f, 0.f},
                  {0.f, 0.f, 0.f, 0.f}};

#pragma unroll
  for (int kc = 0; kc < 4; kc++) {
#pragma unroll
    for (int ot = 0; ot < 4; ot++) {
      int base = (((kc << 2) | ot) * 64 + l) * 8;
      short8 bhi = *(const short8*)&whi[base];
      short8 blo = *(const short8*)&wlo[base];
      acc[ot] = __builtin_amdgcn_mfma_f32_16x16x32_bf16(ahi[kc], bhi, acc[ot],
                                                        0, 0, 0);
      acc[ot] = __builtin_amdgcn_mfma_f32_16x16x32_bf16(ahi[kc], blo, acc[ot],
                                                        0, 0, 0);
      acc[ot] = __builtin_amdgcn_mfma_f32_16x16x32_bf16(alo[kc], bhi, acc[ot],
                                                        0, 0, 0);
    }
  }

  float pa[4] = {0.f, 0.f, 0.f, 0.f};
#pragma unroll
  for (int ot = 0; ot < 4; ot++) {
    float aval = a[ot * 16 + m];
#pragma unroll
    for (int r = 0; r < 4; r++) pa[r] += acc[ot][r] * aval;
  }
  int rowb = row0 + w * 16 + q * 4;
#pragma unroll
  for (int r = 0; r < 4; r++) {
    int row = rowb + r;
    if (row < N_NODES) {
#pragma unroll
      for (int ot = 0; ot < 4; ot++) {
        h[(size_t)row * OUT_DIM + ot * 16 + m] = acc[ot][r];
        h16[(size_t)row * OUT_DIM + ot * 16 + m] = __float2half(acc[ot][r]);
      }
    }
  }
#pragma unroll
  for (int r = 0; r < 4; r++) {
    pa[r] += __shfl_xor(pa[r], 1);
    pa[r] += __shfl_xor(pa[r], 2);
    pa[r] += __shfl_xor(pa[r], 4);
    pa[r] += __shfl_xor(pa[r], 8);
  }
  if (m == 0) {
#pragma unroll
    for (int r = 0; r < 4; r++) {
      int row = rowb + r;
      if (row < N_NODES) ha[row] = pa[r];
    }
  }
}

// ---- Fused sort+gather: run ingest -> LDS counting sort -> reg gather ----
__global__ __launch_bounds__(SG_THREADS) void sortgather_kernel(
    const float* __restrict__ h, const __half* __restrict__ h16,
    const float* __restrict__ ha, const unsigned char* __restrict__ cnt8,
    const unsigned int* __restrict__ pairs, float* __restrict__ out) {
  __shared__ unsigned int plds[MAXB2];  // 10.2 KB
  __shared__ int2 slds[MAXB2];          // 20.5 KB
  __shared__ float had[128];
  __shared__ int hist[128];
  __shared__ int scn[128];
  __shared__ int cur[128];
  __shared__ int cntv[BIN_NBLK];
  __shared__ int tot;
  int b = blockIdx.x;
  int t = threadIdx.x;
  int node0 = b << 7;

  if (t == 0) tot = 0;
  if (t < BIN_NBLK) cntv[t] = cnt8[t * NB2 + b];
  if (t < 128) {
    int node = node0 + t;
    had[t] = (node < N_NODES) ? ha[node] : 0.f;
    hist[t] = 0;
  }
  __syncthreads();

  // ingest valid run slots, compact into plds, build node histogram
  for (int i = t; i < RUNTOT; i += SG_THREADS) {
    int qb = i >> 6;  // log2(RUNCAP)
    if ((i & (RUNCAP - 1)) < cntv[qb]) {
      unsigned int p = pairs[(size_t)b * RUNTOT + i];
      int pos = atomicAdd(&tot, 1);
      if (pos < MAXB2) {
        plds[pos] = p;
        atomicAdd(&hist[p & 127u], 1);
      }
    }
  }
  __syncthreads();
  int cnt = min(tot, MAXB2);

  int v = (t < 128) ? hist[t] : 0;
  if (t < 128) scn[t] = v;
  __syncthreads();
  for (int off = 1; off < 128; off <<= 1) {
    int u = (t >= off && t < 128) ? scn[t - off] : 0;
    __syncthreads();
    if (t < 128) scn[t] += u;
    __syncthreads();
  }
  if (t < 128) cur[t] = scn[t] - v;  // exclusive prefix
  __syncthreads();
  for (int i = t; i < cnt; i += SG_THREADS) {
    unsigned int p = plds[i];
    int nl = (int)(p & 127u);
    int sb = (int)(p & 0xFFFFFF80u);  // src << 7 == h16 row byte offset
    float ex = edge_ex(had[nl] - ha[sb >> 7]);
    int pos = atomicAdd(&cur[nl], 1);
    slds[pos] = make_int2(sb, __float_as_int(ex));
  }
  __syncthreads();

  // ---- gather phase (verified body): wave wv handles nodes wv, wv+8, ... --
  int wv = t >> 6;
  int lane = t & 63;
  int g = lane >> 3;  // subgroup 0..7
  int l8 = lane & 7;  // cols [8*l8, 8*l8+8)
  const char* h16b = (const char*)h16;
  const float4* h4 = (const float4*)h;
  float4* o4 = (float4*)out;

  for (int nl = wv; nl < 128; nl += 8) {
    int node = node0 + nl;
    if (node >= N_NODES) break;  // uniform per wave
    int endp = scn[nl];
    int begp = endp - hist[nl];
    float4 hd0 = h4[(size_t)node * (OUT_DIM / 4) + l8 * 2];
    float4 hd1 = h4[(size_t)node * (OUT_DIM / 4) + l8 * 2 + 1];
    float acc[8] = {0.f, 0.f, 0.f, 0.f, 0.f, 0.f, 0.f, 0.f};
    float den = 0.f;
    int last = endp - 1;

    // subgroup g covers edges begp+g, +8, +16, ... (stride-8 interleave)
    for (int i0 = begp + g; i0 < endp; i0 += 32) {
      int2 e[4];
      float exv[4];
#pragma unroll
      for (int k = 0; k < 4; k++) {
        int i = i0 + k * 8;
        e[k] = slds[i < endp ? i : last];
        exv[k] = (i < endp) ? __int_as_float(e[k].y) : 0.f;
      }
      uint4 uv[4];
#pragma unroll
      for (int k = 0; k < 4; k++)
        uv[k] = *(const uint4*)(h16b + e[k].x + (l8 << 4));
#pragma unroll
      for (int k = 0; k < 4; k++) {
        union {
          uint4 u;
          __half hh[8];
        } U;
        U.u = uv[k];
        float ex = exv[k];
        den += ex;
#pragma unroll
        for (int j = 0; j < 8; j++)
          acc[j] = fmaf(__half2float(U.hh[j]), ex, acc[j]);  // v_fma_mix_f32
      }
    }

#pragma unroll
    for (int j = 0; j < 8; j++) {
      acc[j] += __shfl_xor(acc[j], 8);
      acc[j] += __shfl_xor(acc[j], 16);
      acc[j] += __shfl_xor(acc[j], 32);
    }
    den += __shfl_xor(den, 8);
    den += __shfl_xor(den, 16);
    den += __shfl_xor(den, 32);

    if (g == 0) {
      bool has = den > 0.f;
      float inv = has ? __builtin_amdgcn_rcpf(den) : 0.f;
      float4 r0, r1;
      r0.x = fmaxf(has ? 2.f * hd0.x - acc[0] * inv : hd0.x, 0.f);
      r0.y = fmaxf(has ? 2.f * hd0.y - acc[1] * inv : hd0.y, 0.f);
      r0.z = fmaxf(has ? 2.f * hd0.z - acc[2] * inv : hd0.z, 0.f);
      r0.w = fmaxf(has ? 2.f * hd0.w - acc[3] * inv : hd0.w, 0.f);
      r1.x = fmaxf(has ? 2.f * hd1.x - acc[4] * inv : hd1.x, 0.f);
      r1.y = fmaxf(has ? 2.f * hd1.y - acc[5] * inv : hd1.y, 0.f);
      r1.z = fmaxf(has ? 2.f * hd1.z - acc[6] * inv : hd1.z, 0.f);
      r1.w = fmaxf(has ? 2.f * hd1.w - acc[7] * inv : hd1.w, 0.f);
      o4[(size_t)node * (OUT_DIM / 4) + l8 * 2] = r0;
      o4[(size_t)node * (OUT_DIM / 4) + l8 * 2 + 1] = r1;
    }
  }
}

extern "C" void kernel_launch(void* const* d_in, const int* in_sizes, int n_in,
                              void* d_out, int out_size, void* d_ws,
                              size_t ws_size, hipStream_t stream) {
  const float* h_init = (const float*)d_in[0];
  const float* W1 = (const float*)d_in[1];
  const float* a = (const float*)d_in[2];
  const int* src = (const int*)d_in[3];
  const int* dst = (const int*)d_in[4];
  float* out = (float*)d_out;

  // workspace layout (~59 MB)
  float* h = (float*)d_ws;                                 // 25.6 MB
  __half* h16 = (__half*)(h + (size_t)N_NODES * OUT_DIM);  // 12.8 MB
  float* ha = (float*)(h16 + (size_t)N_NODES * OUT_DIM);   // 0.4 MB
  unsigned int* pairs = (unsigned int*)(ha + N_NODES);     // 20.0 MB
  unsigned char* cnt8 =
      (unsigned char*)(pairs + (size_t)NB2 * RUNTOT);      // 78 KB

  fused_pb_kernel<<<PB_GRID, 256, 0, stream>>>(h_init, W1, a, src, dst, h, h16,
                                               ha, pairs, cnt8);
  sortgather_kernel<<<NB2, SG_THREADS, 0, stream>>>(h, h16, ha, cnt8, pairs,
                                                    out);
}

// Round 8
// 183.011 us; speedup vs baseline: 1.1868x; 1.1868x over previous
//
#include <hip/hip_runtime.h>
#include <hip/hip_fp16.h>

#define N_NODES 100000
#define N_EDGES 1600000
#define IN_DIM 128
#define OUT_DIM 64

#define PROJ_BLKS 1563  // ceil(N_NODES/64): 64 rows per block (4 waves x 16)

// Buckets of 128 nodes: bucket = dst >> 7.
#define NB2 782        // ceil(N_NODES/128)
#define MAXB2 2560     // Binom(1.6M,128/1e5): mean 2048, sigma 45; +11 sigma
#define CUR_STRIDE 16  // one cursor per 64B line (no cross-XCD false sharing)

#define BIN_NBLK 250
#define BIN_CHUNK 6400    // BIN_NBLK * BIN_CHUNK == N_EDGES
#define BIN_THREADS 1024  // 16 waves/block: latency chains need TLP

#define SG_THREADS 512  // 8 waves; ~33KB LDS -> 4 blocks/CU

typedef short short8 __attribute__((ext_vector_type(8)));
typedef float f32x4 __attribute__((ext_vector_type(4)));

__device__ __forceinline__ short bf16_trunc(float x) {
  return (short)(__float_as_uint(x) >> 16);
}
__device__ __forceinline__ float bf16_tof(short s) {
  return __uint_as_float(((unsigned)(unsigned short)s) << 16);
}
__device__ __forceinline__ float edge_ex(float p) {
  float t2 = __expf(2.f * p);
  float th = 1.f - 2.f * __builtin_amdgcn_rcpf(t2 + 1.f);
  return __expf(th);
}

// ---------------- Kernel 1: MFMA projection (verified body) ----------------
// Writes h16 (fp16 rows) + ha only; fp32 h dropped (epilogue reads h16 — R6
// verified absmax unchanged).
__global__ __launch_bounds__(256) void fat1_kernel(
    const float* __restrict__ h_init, const float* __restrict__ W1,
    const float* __restrict__ a, __half* __restrict__ h16,
    float* __restrict__ ha) {
  __shared__ short whi[16 * 64 * 8];  // 16 KB
  __shared__ short wlo[16 * 64 * 8];  // 16 KB

  // stage W as bf16 hi/lo B-fragments (frag f=kc*4+ot, B[k][n]=W1[ot*16+n][k])
  for (int idx = threadIdx.x; idx < 16 * 64; idx += 256) {
    int f = idx >> 6;
    int l = idx & 63;
    int kc = f >> 2, ot = f & 3;
    const float* wsrc =
        W1 + (ot * 16 + (l & 15)) * IN_DIM + kc * 32 + (l >> 4) * 8;
    short hi[8], lo[8];
#pragma unroll
    for (int j = 0; j < 8; j++) {
      float x = wsrc[j];
      short hv = bf16_trunc(x);
      hi[j] = hv;
      lo[j] = bf16_trunc(x - bf16_tof(hv));
    }
    *(short8*)&whi[idx * 8] = *(const short8*)hi;
    *(short8*)&wlo[idx * 8] = *(const short8*)lo;
  }

  int row0 = blockIdx.x * 64;
  int w = threadIdx.x >> 6;
  int l = threadIdx.x & 63;
  int m = l & 15;
  int q = l >> 4;

  int arow = row0 + w * 16 + m;
  if (arow >= N_NODES) arow = N_NODES - 1;
  const float* xsrc = h_init + (size_t)arow * IN_DIM + q * 8;

  short8 ahi[4], alo[4];
#pragma unroll
  for (int kc = 0; kc < 4; kc++) {
    float xv[8];
    *(float4*)&xv[0] = *(const float4*)(xsrc + kc * 32);
    *(float4*)&xv[4] = *(const float4*)(xsrc + kc * 32 + 4);
    short hi[8], lo[8];
#pragma unroll
    for (int j = 0; j < 8; j++) {
      short hv = bf16_trunc(xv[j]);
      hi[j] = hv;
      lo[j] = bf16_trunc(xv[j] - bf16_tof(hv));
    }
    ahi[kc] = *(const short8*)hi;
    alo[kc] = *(const short8*)lo;
  }
  __syncthreads();

  f32x4 acc[4] = {{0.f, 0.f, 0.f, 0.f},
                  {0.f, 0.f, 0.f, 0.f},
                  {0.f, 0.f, 0.f, 0.f},
                  {0.f, 0.f, 0.f, 0.f}};

#pragma unroll
  for (int kc = 0; kc < 4; kc++) {
#pragma unroll
    for (int ot = 0; ot < 4; ot++) {
      int base = (((kc << 2) | ot) * 64 + l) * 8;
      short8 bhi = *(const short8*)&whi[base];
      short8 blo = *(const short8*)&wlo[base];
      acc[ot] = __builtin_amdgcn_mfma_f32_16x16x32_bf16(ahi[kc], bhi, acc[ot],
                                                        0, 0, 0);
      acc[ot] = __builtin_amdgcn_mfma_f32_16x16x32_bf16(ahi[kc], blo, acc[ot],
                                                        0, 0, 0);
      acc[ot] = __builtin_amdgcn_mfma_f32_16x16x32_bf16(alo[kc], bhi, acc[ot],
                                                        0, 0, 0);
    }
  }

  float pa[4] = {0.f, 0.f, 0.f, 0.f};
#pragma unroll
  for (int ot = 0; ot < 4; ot++) {
    float aval = a[ot * 16 + m];
#pragma unroll
    for (int r = 0; r < 4; r++) pa[r] += acc[ot][r] * aval;
  }
  int rowb = row0 + w * 16 + q * 4;
#pragma unroll
  for (int r = 0; r < 4; r++) {
    int row = rowb + r;
    if (row < N_NODES) {
#pragma unroll
      for (int ot = 0; ot < 4; ot++)
        h16[(size_t)row * OUT_DIM + ot * 16 + m] = __float2half(acc[ot][r]);
    }
  }
#pragma unroll
  for (int r = 0; r < 4; r++) {
    pa[r] += __shfl_xor(pa[r], 1);
    pa[r] += __shfl_xor(pa[r], 2);
    pa[r] += __shfl_xor(pa[r], 4);
    pa[r] += __shfl_xor(pa[r], 8);
  }
  if (m == 0) {
#pragma unroll
    for (int r = 0; r < 4; r++) {
      int row = rowb + r;
      if (row < N_NODES) ha[row] = pa[r];
    }
  }
}

// ------- Partition into static 128-node bucket regions (R5-verified) -------
__global__ __launch_bounds__(BIN_THREADS) void bin_scatter_kernel(
    const int* __restrict__ src, const int* __restrict__ dst,
    int* __restrict__ bucket_cursor, unsigned int* __restrict__ pairs) {
  __shared__ int hst[NB2];
  __shared__ int cur[NB2];
  __shared__ int dlds[BIN_CHUNK];  // 25.6 KB dst cache
  int t = threadIdx.x;
  for (int i = t; i < NB2; i += BIN_THREADS) hst[i] = 0;
  __syncthreads();
  int beg = blockIdx.x * BIN_CHUNK;
  for (int e = t; e < BIN_CHUNK; e += BIN_THREADS) {
    int d = dst[beg + e];
    dlds[e] = d;
    atomicAdd(&hst[d >> 7], 1);
  }
  __syncthreads();
  for (int i = t; i < NB2; i += BIN_THREADS) {
    int c = hst[i];
    cur[i] =
        (c > 0) ? atomicAdd(&bucket_cursor[i * CUR_STRIDE], c) + i * MAXB2 : 0;
  }
  __syncthreads();
  for (int e = t; e < BIN_CHUNK; e += BIN_THREADS) {
    int d = dlds[e];
    int pos = atomicAdd(&cur[d >> 7], 1);
    pairs[pos] = ((unsigned int)src[beg + e] << 7) | (unsigned int)(d & 127);
  }
}

// ---- Fused sort+gather: in-LDS counting sort, then SUBGROUP-PER-NODE ------
// Sort phase: R5-verified (hist -> scan -> ex-scatter into slds).
// Gather phase: 64 subgroups of 8 lanes; subgroup sg owns nodes sg and sg+64.
// 8 nodes per wave run CONCURRENTLY (4x loads in flight vs serial-node) and
// the cross-subgroup shuffle reduce disappears (acc/den are subgroup-local).
__global__ __launch_bounds__(SG_THREADS) void sortgather_kernel(
    const __half* __restrict__ h16, const float* __restrict__ ha,
    const int* __restrict__ bucket_cursor, const unsigned int* __restrict__
        pairs, float* __restrict__ out) {
  __shared__ unsigned int plds[MAXB2];  // 10.2 KB
  __shared__ int2 slds[MAXB2];          // 20.5 KB
  __shared__ float had[128];
  __shared__ int hist[128];
  __shared__ int scn[128];
  __shared__ int cur[128];
  int b = blockIdx.x;
  int t = threadIdx.x;
  int node0 = b << 7;
  int cnt = min(bucket_cursor[b * CUR_STRIDE], MAXB2);

  if (t < 128) {
    int node = node0 + t;
    had[t] = (node < N_NODES) ? ha[node] : 0.f;
    hist[t] = 0;
  }
  __syncthreads();
  for (int i = t; i < cnt; i += SG_THREADS) {
    unsigned int p = pairs[(size_t)b * MAXB2 + i];
    plds[i] = p;
    atomicAdd(&hist[p & 127u], 1);
  }
  __syncthreads();
  int v = (t < 128) ? hist[t] : 0;
  if (t < 128) scn[t] = v;
  __syncthreads();
  for (int off = 1; off < 128; off <<= 1) {
    int u = (t >= off && t < 128) ? scn[t - off] : 0;
    __syncthreads();
    if (t < 128) scn[t] += u;
    __syncthreads();
  }
  if (t < 128) cur[t] = scn[t] - v;  // exclusive prefix
  __syncthreads();
  for (int i = t; i < cnt; i += SG_THREADS) {
    unsigned int p = plds[i];
    int nl = (int)(p & 127u);
    int sb = (int)(p & 0xFFFFFF80u);  // src << 7 == h16 row byte offset
    float ex = edge_ex(had[nl] - ha[sb >> 7]);
    int pos = atomicAdd(&cur[nl], 1);
    slds[pos] = make_int2(sb, __float_as_int(ex));
  }
  __syncthreads();

  // ---- gather: subgroup sg (8 lanes) owns nodes sg, sg+64 ----
  int sg = t >> 3;  // subgroup 0..63
  int l8 = t & 7;   // cols [8*l8, 8*l8+8)
  const char* h16b = (const char*)h16;
  float4* o4 = (float4*)out;

  for (int nl = sg; nl < 128; nl += 64) {
    int node = node0 + nl;
    if (node >= N_NODES) continue;  // only trims the last bucket
    int endp = scn[nl];
    int begp = endp - hist[nl];
    // hoist dst-node h16 row (epilogue operand) to overlap gather latency
    union {
      uint4 u;
      __half hh[8];
    } HD;
    HD.u = *(const uint4*)(h16b + ((size_t)node << 7) + (l8 << 4));
    float acc[8] = {0.f, 0.f, 0.f, 0.f, 0.f, 0.f, 0.f, 0.f};
    float den = 0.f;
    int last = endp - 1;

    for (int base = begp; base < endp; base += 4) {  // 4 edges in flight
      int2 e[4];
      float exv[4];
#pragma unroll
      for (int k = 0; k < 4; k++) {
        int i = base + k;
        e[k] = slds[i < endp ? i : last];
        exv[k] = (i < endp) ? __int_as_float(e[k].y) : 0.f;
      }
      uint4 uv[4];
#pragma unroll
      for (int k = 0; k < 4; k++)
        uv[k] = *(const uint4*)(h16b + e[k].x + (l8 << 4));
#pragma unroll
      for (int k = 0; k < 4; k++) {
        union {
          uint4 u;
          __half hh[8];
        } U;
        U.u = uv[k];
        float ex = exv[k];
        den += ex;
#pragma unroll
        for (int j = 0; j < 8; j++)
          acc[j] = fmaf(__half2float(U.hh[j]), ex, acc[j]);  // v_fma_mix_f32
      }
    }

    bool has = den > 0.f;
    float inv = has ? __builtin_amdgcn_rcpf(den) : 0.f;
    float hd[8];
#pragma unroll
    for (int j = 0; j < 8; j++) hd[j] = __half2float(HD.hh[j]);
    float4 r0, r1;
    r0.x = fmaxf(has ? 2.f * hd[0] - acc[0] * inv : hd[0], 0.f);
    r0.y = fmaxf(has ? 2.f * hd[1] - acc[1] * inv : hd[1], 0.f);
    r0.z = fmaxf(has ? 2.f * hd[2] - acc[2] * inv : hd[2], 0.f);
    r0.w = fmaxf(has ? 2.f * hd[3] - acc[3] * inv : hd[3], 0.f);
    r1.x = fmaxf(has ? 2.f * hd[4] - acc[4] * inv : hd[4], 0.f);
    r1.y = fmaxf(has ? 2.f * hd[5] - acc[5] * inv : hd[5], 0.f);
    r1.z = fmaxf(has ? 2.f * hd[6] - acc[6] * inv : hd[6], 0.f);
    r1.w = fmaxf(has ? 2.f * hd[7] - acc[7] * inv : hd[7], 0.f);
    o4[(size_t)node * (OUT_DIM / 4) + l8 * 2] = r0;
    o4[(size_t)node * (OUT_DIM / 4) + l8 * 2 + 1] = r1;
  }
}

extern "C" void kernel_launch(void* const* d_in, const int* in_sizes, int n_in,
                              void* d_out, int out_size, void* d_ws,
                              size_t ws_size, hipStream_t stream) {
  const float* h_init = (const float*)d_in[0];
  const float* W1 = (const float*)d_in[1];
  const float* a = (const float*)d_in[2];
  const int* src = (const int*)d_in[3];
  const int* dst = (const int*)d_in[4];
  float* out = (float*)d_out;

  // workspace layout (~22 MB)
  __half* h16 = (__half*)d_ws;                              // 12.8 MB
  float* ha = (float*)(h16 + (size_t)N_NODES * OUT_DIM);    // 0.4 MB
  unsigned int* pairs = (unsigned int*)(ha + N_NODES);      // 8.0 MB
  int* bucket_cursor = (int*)(pairs + (size_t)NB2 * MAXB2); // 782*16

  hipMemsetAsync(bucket_cursor, 0, NB2 * CUR_STRIDE * sizeof(int), stream);
  fat1_kernel<<<PROJ_BLKS, 256, 0, stream>>>(h_init, W1, a, h16, ha);
  bin_scatter_kernel<<<BIN_NBLK, BIN_THREADS, 0, stream>>>(src, dst,
                                                           bucket_cursor,
                                                           pairs);
  sortgather_kernel<<<NB2, SG_THREADS, 0, stream>>>(h16, ha, bucket_cursor,
                                                    pairs, out);
}